// Round 3
// baseline (982.355 us; speedup 1.0000x reference)
//
#include <hip/hip_runtime.h>
#include <stdint.h>

// ASH percentile-threshold, round 3: register-persistent single-read design.
// One 512-thread block per row (B=512). Each thread holds the row's 49 float4
// in VGPRs (196 regs). Exactly one global read + one global write:
//   - load row -> regs (nontemporal)
//   - 3-level radix select (11/11/10 bits) via LDS histograms fed from regs
//   - threshold + write from regs (nontemporal)

typedef float v4f __attribute__((ext_vector_type(4)));

constexpr int ROW_LEN = 2048 * 49;          // 100352
constexpr int THREADS = 512;
constexpr int VEC4    = ROW_LEN / 4;        // 25088
constexpr int PER     = VEC4 / THREADS;     // 49 exactly, no tail

__device__ __forceinline__ uint32_t f2s(float f) {
    uint32_t u = __float_as_uint(f);
    return (u & 0x80000000u) ? ~u : (u | 0x80000000u);
}
__device__ __forceinline__ float s2f(uint32_t u) {
    uint32_t b = (u & 0x80000000u) ? (u ^ 0x80000000u) : ~u;
    return __uint_as_float(b);
}

// Block-wide: find bucket b with prefix[b] <= target < prefix[b]+hist[b].
// sout[0]=bucket, sout[1]=count strictly below bucket. 2 barriers (shfl scan).
template <int NB>
__device__ __forceinline__ void select_bucket(const uint32_t* __restrict__ hist,
                                              uint32_t target,
                                              uint32_t* wsum, uint32_t* sout) {
    const int tid  = threadIdx.x;
    const int lane = tid & 63;
    const int wid  = tid >> 6;
    constexpr int CH = NB / THREADS;    // 4 or 2
    uint32_t c[CH];
    uint32_t s = 0;
#pragma unroll
    for (int j = 0; j < CH; ++j) { c[j] = hist[tid * CH + j]; s += c[j]; }
    // wave-inclusive scan of per-thread sums
    uint32_t inc = s;
#pragma unroll
    for (int d = 1; d < 64; d <<= 1) {
        uint32_t v = __shfl_up(inc, d, 64);
        if (lane >= d) inc += v;
    }
    if (lane == 63) wsum[wid] = inc;
    __syncthreads();
    uint32_t off = 0;
#pragma unroll
    for (int w = 0; w < 8; ++w) off += (w < wid) ? wsum[w] : 0u;
    uint32_t run = off + inc - s;       // exclusive prefix of this thread's chunk
#pragma unroll
    for (int j = 0; j < CH; ++j) {
        if (c[j] != 0u && target >= run && target < run + c[j]) {
            sout[0] = (uint32_t)(tid * CH + j);   // unique writer
            sout[1] = run;
        }
        run += c[j];
    }
    __syncthreads();
}

__global__ __launch_bounds__(THREADS, 2)
void ash_kernel(const float* __restrict__ x, const int* __restrict__ kp,
                float* __restrict__ out) {
    __shared__ uint32_t hist[4][2048];   // L1: 4x replicated; L2/L3: hist[0]/hist[1]
    __shared__ uint32_t wsum[8];
    __shared__ uint32_t sout[4];

    const int tid = threadIdx.x;
    const size_t rowoff = (size_t)blockIdx.x * (size_t)ROW_LEN;
    const v4f* __restrict__ xr = reinterpret_cast<const v4f*>(x + rowoff);

    // ---- order-statistic indices (np.percentile linear interpolation)
    const int kpv = *kp;
    double q = (double)kpv / 100.0;
    double vidx = q * (double)(ROW_LEN - 1);
    if (vidx < 0.0) vidx = 0.0;
    if (vidx > (double)(ROW_LEN - 1)) vidx = (double)(ROW_LEN - 1);
    uint32_t k0 = (uint32_t)vidx;
    double frac = vidx - (double)k0;
    uint32_t k1 = (k0 + 1u < (uint32_t)ROW_LEN) ? k0 + 1u : k0;

    // ---- single global read: whole row into registers
    v4f d[PER];
#pragma unroll
    for (int i = 0; i < PER; ++i)
        d[i] = __builtin_nontemporal_load(&xr[i * THREADS + tid]);

    // ---- L1: histogram of key>>21 (4x replicated, one replica per 2 waves)
    {
        uint32_t* hf = &hist[0][0];
        for (int i = tid; i < 4 * 2048; i += THREADS) hf[i] = 0u;
    }
    __syncthreads();
    {
        uint32_t* hr = hist[(tid >> 7) & 3];
#pragma unroll
        for (int i = 0; i < PER; ++i) {
            atomicAdd(&hr[f2s(d[i].x) >> 21], 1u);
            atomicAdd(&hr[f2s(d[i].y) >> 21], 1u);
            atomicAdd(&hr[f2s(d[i].z) >> 21], 1u);
            atomicAdd(&hr[f2s(d[i].w) >> 21], 1u);
        }
    }
    __syncthreads();
    for (int i = tid; i < 2048; i += THREADS)
        hist[0][i] += hist[1][i] + hist[2][i] + hist[3][i];
    __syncthreads();
    select_bucket<2048>(hist[0], k0, wsum, sout);
    select_bucket<2048>(hist[0], k1, wsum, sout + 2);
    const uint32_t p0 = sout[0]; uint32_t base0 = sout[1];
    const uint32_t p1 = sout[2]; uint32_t base1 = sout[3];
    __syncthreads();

    // ---- L2: bits 20..10 within buckets p0 (and p1 if different)
    for (int i = tid; i < 2048; i += THREADS) { hist[0][i] = 0u; hist[1][i] = 0u; }
    __syncthreads();
    {
        const bool same1 = (p0 == p1);
#pragma unroll
        for (int i = 0; i < PER; ++i) {
            uint32_t u;
            u = f2s(d[i].x);
            if ((u >> 21) == p0) atomicAdd(&hist[0][(u >> 10) & 0x7FFu], 1u);
            else if (!same1 && (u >> 21) == p1) atomicAdd(&hist[1][(u >> 10) & 0x7FFu], 1u);
            u = f2s(d[i].y);
            if ((u >> 21) == p0) atomicAdd(&hist[0][(u >> 10) & 0x7FFu], 1u);
            else if (!same1 && (u >> 21) == p1) atomicAdd(&hist[1][(u >> 10) & 0x7FFu], 1u);
            u = f2s(d[i].z);
            if ((u >> 21) == p0) atomicAdd(&hist[0][(u >> 10) & 0x7FFu], 1u);
            else if (!same1 && (u >> 21) == p1) atomicAdd(&hist[1][(u >> 10) & 0x7FFu], 1u);
            u = f2s(d[i].w);
            if ((u >> 21) == p0) atomicAdd(&hist[0][(u >> 10) & 0x7FFu], 1u);
            else if (!same1 && (u >> 21) == p1) atomicAdd(&hist[1][(u >> 10) & 0x7FFu], 1u);
        }
        __syncthreads();
        select_bucket<2048>(hist[0], k0 - base0, wsum, sout);
        select_bucket<2048>(same1 ? hist[0] : hist[1], k1 - base1, wsum, sout + 2);
    }
    const uint32_t m0 = sout[0]; base0 += sout[1];
    const uint32_t m1 = sout[2]; base1 += sout[3];
    const uint32_t q0 = (p0 << 11) | m0;
    const uint32_t q1 = (p1 << 11) | m1;
    __syncthreads();

    // ---- L3: bits 9..0 within 22-bit prefixes q0 (and q1 if different)
    for (int i = tid; i < 2048; i += THREADS) { hist[0][i] = 0u; hist[1][i] = 0u; }
    __syncthreads();
    {
        const bool same2 = (q0 == q1);
#pragma unroll
        for (int i = 0; i < PER; ++i) {
            uint32_t u;
            u = f2s(d[i].x);
            if ((u >> 10) == q0) atomicAdd(&hist[0][u & 0x3FFu], 1u);
            else if (!same2 && (u >> 10) == q1) atomicAdd(&hist[1][u & 0x3FFu], 1u);
            u = f2s(d[i].y);
            if ((u >> 10) == q0) atomicAdd(&hist[0][u & 0x3FFu], 1u);
            else if (!same2 && (u >> 10) == q1) atomicAdd(&hist[1][u & 0x3FFu], 1u);
            u = f2s(d[i].z);
            if ((u >> 10) == q0) atomicAdd(&hist[0][u & 0x3FFu], 1u);
            else if (!same2 && (u >> 10) == q1) atomicAdd(&hist[1][u & 0x3FFu], 1u);
            u = f2s(d[i].w);
            if ((u >> 10) == q0) atomicAdd(&hist[0][u & 0x3FFu], 1u);
            else if (!same2 && (u >> 10) == q1) atomicAdd(&hist[1][u & 0x3FFu], 1u);
        }
        __syncthreads();
        select_bucket<1024>(hist[0], k0 - base0, wsum, sout);
        select_bucket<1024>(same2 ? hist[0] : hist[1], k1 - base1, wsum, sout + 2);
    }
    const uint32_t key0 = (q0 << 10) | sout[0];
    const uint32_t key1 = (q1 << 10) | sout[2];

    // ---- threshold (numpy _lerp in f64, cast to f32) — all threads compute
    double v0 = (double)s2f(key0);
    double v1 = (double)s2f(key1);
    double th_d = (frac >= 0.5) ? v1 - (v1 - v0) * (1.0 - frac)
                                : v0 + (v1 - v0) * frac;
    const float th = (float)th_d;

    // ---- single global write: threshold from registers
    v4f* __restrict__ orow = reinterpret_cast<v4f*>(out + rowoff);
#pragma unroll
    for (int i = 0; i < PER; ++i) {
        v4f a = d[i], r;
        r.x = (a.x > th) ? a.x : 0.0f;
        r.y = (a.y > th) ? a.y : 0.0f;
        r.z = (a.z > th) ? a.z : 0.0f;
        r.w = (a.w > th) ? a.w : 0.0f;
        __builtin_nontemporal_store(r, &orow[i * THREADS + tid]);
    }
}

extern "C" void kernel_launch(void* const* d_in, const int* in_sizes, int n_in,
                              void* d_out, int out_size, void* d_ws, size_t ws_size,
                              hipStream_t stream) {
    const float* x  = (const float*)d_in[0];
    const int*   kp = (const int*)d_in[1];
    float*       out = (float*)d_out;
    const int rows = in_sizes[0] / ROW_LEN;   // 512
    hipLaunchKernelGGL(ash_kernel, dim3(rows), dim3(THREADS), 0, stream,
                       x, kp, out);
}